// Round 11
// baseline (287283.569 us; speedup 1.0000x reference)
//
#include <hip/hip_runtime.h>

// LSTM (H=64, IN=1) sequential scan, T=524288, one block of 256 threads on
// one CU (4 waves). Thread (w=tid>>6, l=tid&63) owns gate-type gt=l&3 of
// hidden unit u=16w+(l>>2): all 4 gates of a unit live in one DPP quad ->
// gate exchange is 3 quad_perm DPP moves + cndmask selects (no LDS).
// One __syncthreads per step (cross-wave h broadcast, double-buffered).
//
// Round-3 post-mortem: VGPR=44 + FETCH_SIZE=1.1GB proved the compiler
// REMATERIALIZES the invariant W_hh loads inside the t-loop (invariant
// loads are trivially-remat for RA) instead of keeping them live. Fix:
// opaque asm "+v" identity on each weight float makes the values
// non-rematerializable -> RA must keep them register-resident.
// (Rounds 4-10: container filesystem full -> environment failure; rounds
// 9-10 failed before the source was even pushed. Needs operator cleanup
// or pod recycle. Same experiment, verbatim.)

template <int CTRL>
__device__ __forceinline__ float qperm(float x) {
    return __int_as_float(
        __builtin_amdgcn_update_dpp(__float_as_int(x), __float_as_int(x),
                                    CTRL, 0xf, 0xf, false));
}

// Opaque identity on a float4: breaks rematerialization of the feeding loads.
#define PIN4(v) asm volatile("" : "+v"(v.x), "+v"(v.y), "+v"(v.z), "+v"(v.w))

__global__ __launch_bounds__(256, 1)
void lstm_seq_kernel(const float* __restrict__ seq,
                     const float* __restrict__ W_ih,
                     const float* __restrict__ W_hh,
                     const float* __restrict__ b_ih,
                     const float* __restrict__ b_hh,
                     const float* __restrict__ W_lin,
                     const float* __restrict__ b_lin,
                     float* __restrict__ out,
                     int T)
{
    __shared__ float h_buf[2][64];     // double-buffered hidden state
    __shared__ float x_lds[2][256];    // double-buffered input chunks

    const int tid = threadIdx.x;
    const int w   = tid >> 6;
    const int l   = tid & 63;
    const int gt  = l & 3;                 // 0=i 1=f 2=g(tanh) 3=o
    const int u   = (w << 4) + (l >> 2);   // hidden unit 0..63
    const int row = (gt << 6) + u;         // row in [4H], PyTorch order

    // ---- W_hh row pinned in 16 float4 registers (non-remat via PIN4) ----
    const float4* wp = reinterpret_cast<const float4*>(W_hh + row * 64);
    float4 w0 = wp[0],  w1 = wp[1],  w2 = wp[2],  w3 = wp[3];
    float4 w4 = wp[4],  w5 = wp[5],  w6 = wp[6],  w7 = wp[7];
    float4 w8 = wp[8],  w9 = wp[9],  wA = wp[10], wB = wp[11];
    float4 wC = wp[12], wD = wp[13], wE = wp[14], wF = wp[15];
    PIN4(w0); PIN4(w1); PIN4(w2); PIN4(w3);
    PIN4(w4); PIN4(w5); PIN4(w6); PIN4(w7);
    PIN4(w8); PIN4(w9); PIN4(wA); PIN4(wB);
    PIN4(wC); PIN4(wD); PIN4(wE); PIN4(wF);

    float wih  = W_ih[row];
    float bias = b_ih[row] + b_hh[row];
    asm volatile("" : "+v"(wih), "+v"(bias));

    // branchless activation: a = osc * sigmoid(asc*g) + ooff (tanh for gt==2)
    const float asc  = (gt == 2) ? 2.0f : 1.0f;
    const float osc  = (gt == 2) ? 2.0f : 1.0f;
    const float ooff = (gt == 2) ? -1.0f : 0.0f;
    const bool  m1   = (gt & 1) != 0;      // loop-invariant select masks
    const bool  m2   = (gt & 2) != 0;
    const bool  wr_h = (gt == 0);

    if (tid < 64) { h_buf[0][tid] = 0.0f; h_buf[1][tid] = 0.0f; }
    x_lds[0][tid] = seq[tid];
    float c = 0.0f;
    __syncthreads();

    for (int t = 0; t < T; ++t) {
        const int tm = t & 255;
        const int cb = (t >> 8) & 1;
        if (tm == 0) {                      // prefetch next 256-step chunk
            const int idx = t + 256 + tid;
            if (idx < T) x_lds[cb ^ 1][tid] = seq[idx];
        }
        const float  xv  = x_lds[cb][tm];
        const float4* hb = reinterpret_cast<const float4*>(h_buf[t & 1]);

        // ---- gate preactivation: wih*x + bias + dot(Wrow, h) ----
        float a0 = fmaf(xv, wih, bias);
        float a1 = 0.0f, a2 = 0.0f, a3 = 0.0f;
#define MAC(W, J) { const float4 hv = hb[J];                 \
        a0 = fmaf(W.x, hv.x, a0); a1 = fmaf(W.y, hv.y, a1);  \
        a2 = fmaf(W.z, hv.z, a2); a3 = fmaf(W.w, hv.w, a3); }
        MAC(w0, 0)  MAC(w1, 1)  MAC(w2, 2)  MAC(w3, 3)
        MAC(w4, 4)  MAC(w5, 5)  MAC(w6, 6)  MAC(w7, 7)
        MAC(w8, 8)  MAC(w9, 9)  MAC(wA, 10) MAC(wB, 11)
        MAC(wC, 12) MAC(wD, 13) MAC(wE, 14) MAC(wF, 15)
#undef MAC
        const float g = (a0 + a1) + (a2 + a3);

        // activation (sigmoid for i,f,o; tanh = 2*sig(2x)-1 for g)
        const float s = __builtin_amdgcn_rcpf(1.0f + __expf(-(g * asc)));
        const float a = fmaf(s, osc, ooff);

        // ---- quad DPP exchange: lane gets gates {gt, gt^1, gt^2, gt^3} ----
        const float s1 = qperm<0xB1>(a);    // quad_perm [1,0,3,2] -> gt^1
        const float s2 = qperm<0x4E>(a);    // quad_perm [2,3,0,1] -> gt^2
        const float s3 = qperm<0x1B>(a);    // quad_perm [3,2,1,0] -> gt^3
        // i*g: even gt -> a*s2, odd gt -> s1*s3
        const float ig = m1 ? (s1 * s3) : (a * s2);
        // f (gate 1): gt=0->s1 1->a 2->s3 3->s2
        const float f  = m1 ? (m2 ? s2 : a) : (m2 ? s3 : s1);
        // o (gate 3): gt=0->s3 1->s2 2->s1 3->a
        const float o  = m1 ? (m2 ? a : s2) : (m2 ? s1 : s3);

        // ---- cell + hidden update (replicated across the quad) ----
        c = fmaf(f, c, ig);
        const float tc = 1.0f - 2.0f * __builtin_amdgcn_rcpf(1.0f + __expf(2.0f * c));
        const float hu = o * tc;
        if (wr_h) h_buf[(t + 1) & 1][u] = hu;
        __syncthreads();
    }

    // head: out = dot(W_lin, h_last) + b_lin
    if (tid < 64) {
        float v = h_buf[T & 1][tid] * W_lin[tid];
#pragma unroll
        for (int m = 32; m >= 1; m >>= 1) v += __shfl_xor(v, m, 64);
        if (tid == 0) out[0] = v + b_lin[0];
    }
}

extern "C" void kernel_launch(void* const* d_in, const int* in_sizes, int n_in,
                              void* d_out, int out_size, void* d_ws, size_t ws_size,
                              hipStream_t stream) {
    const float* seq   = (const float*)d_in[0];
    const float* W_ih  = (const float*)d_in[1];
    const float* W_hh  = (const float*)d_in[2];
    const float* b_ih  = (const float*)d_in[3];
    const float* b_hh  = (const float*)d_in[4];
    const float* W_lin = (const float*)d_in[5];
    const float* b_lin = (const float*)d_in[6];
    float* out = (float*)d_out;
    const int T = in_sizes[0];

    hipLaunchKernelGGL(lstm_seq_kernel, dim3(1), dim3(256), 0, stream,
                       seq, W_ih, W_hh, b_ih, b_hh, W_lin, b_lin, out, T);
}

// Round 12
// 239733.228 us; speedup vs baseline: 1.1983x; 1.1983x over previous
//
#include <hip/hip_runtime.h>

// LSTM (H=64, IN=1) sequential scan, T=524288, one block of 256 threads on
// one CU (4 waves). Thread (w=tid>>6, l=tid&63) owns gate-type gt=l&3 of
// hidden unit u=16w+(l>>2): all 4 gates of a unit live in one DPP quad ->
// gate exchange is 3 quad_perm DPP moves + cndmask selects (no LDS).
// One __syncthreads per step (cross-wave h broadcast, double-buffered).
//
// Round-11 post-mortem: PIN4 alone did NOT raise VGPR (still 44) or cut
// FETCH_SIZE (still 1.1GB) -> RA SPILLED the pinned weights to scratch.
// __launch_bounds__(256,1) only sets MIN waves/EU; the backend still
// TARGETS high occupancy (<=64 VGPR for 8 waves/SIMD) and spills to get
// there. Grid is ONE block -> occupancy is worthless here. Fix: clamp the
// occupancy target itself with amdgpu_waves_per_eu(1,1) (max=1) so the RA
// budget becomes 512 VGPRs and the pinned weights stay resident.

template <int CTRL>
__device__ __forceinline__ float qperm(float x) {
    return __int_as_float(
        __builtin_amdgcn_update_dpp(__float_as_int(x), __float_as_int(x),
                                    CTRL, 0xf, 0xf, false));
}

// Opaque identity on a float4: breaks rematerialization of the feeding loads.
#define PIN4(v) asm volatile("" : "+v"(v.x), "+v"(v.y), "+v"(v.z), "+v"(v.w))

__global__ __attribute__((amdgpu_flat_work_group_size(256, 256),
                          amdgpu_waves_per_eu(1, 1)))
void lstm_seq_kernel(const float* __restrict__ seq,
                     const float* __restrict__ W_ih,
                     const float* __restrict__ W_hh,
                     const float* __restrict__ b_ih,
                     const float* __restrict__ b_hh,
                     const float* __restrict__ W_lin,
                     const float* __restrict__ b_lin,
                     float* __restrict__ out,
                     int T)
{
    __shared__ float h_buf[2][64];     // double-buffered hidden state
    __shared__ float x_lds[2][256];    // double-buffered input chunks

    const int tid = threadIdx.x;
    const int w   = tid >> 6;
    const int l   = tid & 63;
    const int gt  = l & 3;                 // 0=i 1=f 2=g(tanh) 3=o
    const int u   = (w << 4) + (l >> 2);   // hidden unit 0..63
    const int row = (gt << 6) + u;         // row in [4H], PyTorch order

    // ---- W_hh row pinned in 16 float4 registers (non-remat via PIN4) ----
    const float4* wp = reinterpret_cast<const float4*>(W_hh + row * 64);
    float4 w0 = wp[0],  w1 = wp[1],  w2 = wp[2],  w3 = wp[3];
    float4 w4 = wp[4],  w5 = wp[5],  w6 = wp[6],  w7 = wp[7];
    float4 w8 = wp[8],  w9 = wp[9],  wA = wp[10], wB = wp[11];
    float4 wC = wp[12], wD = wp[13], wE = wp[14], wF = wp[15];
    PIN4(w0); PIN4(w1); PIN4(w2); PIN4(w3);
    PIN4(w4); PIN4(w5); PIN4(w6); PIN4(w7);
    PIN4(w8); PIN4(w9); PIN4(wA); PIN4(wB);
    PIN4(wC); PIN4(wD); PIN4(wE); PIN4(wF);

    float wih  = W_ih[row];
    float bias = b_ih[row] + b_hh[row];
    asm volatile("" : "+v"(wih), "+v"(bias));

    // branchless activation: a = osc * sigmoid(asc*g) + ooff (tanh for gt==2)
    const float asc  = (gt == 2) ? 2.0f : 1.0f;
    const float osc  = (gt == 2) ? 2.0f : 1.0f;
    const float ooff = (gt == 2) ? -1.0f : 0.0f;
    const bool  m1   = (gt & 1) != 0;      // loop-invariant select masks
    const bool  m2   = (gt & 2) != 0;
    const bool  wr_h = (gt == 0);

    if (tid < 64) { h_buf[0][tid] = 0.0f; h_buf[1][tid] = 0.0f; }
    x_lds[0][tid] = seq[tid];
    float c = 0.0f;
    __syncthreads();

    for (int t = 0; t < T; ++t) {
        const int tm = t & 255;
        const int cb = (t >> 8) & 1;
        if (tm == 0) {                      // prefetch next 256-step chunk
            const int idx = t + 256 + tid;
            if (idx < T) x_lds[cb ^ 1][tid] = seq[idx];
        }
        const float  xv  = x_lds[cb][tm];
        const float4* hb = reinterpret_cast<const float4*>(h_buf[t & 1]);

        // ---- gate preactivation: wih*x + bias + dot(Wrow, h) ----
        float a0 = fmaf(xv, wih, bias);
        float a1 = 0.0f, a2 = 0.0f, a3 = 0.0f;
#define MAC(W, J) { const float4 hv = hb[J];                 \
        a0 = fmaf(W.x, hv.x, a0); a1 = fmaf(W.y, hv.y, a1);  \
        a2 = fmaf(W.z, hv.z, a2); a3 = fmaf(W.w, hv.w, a3); }
        MAC(w0, 0)  MAC(w1, 1)  MAC(w2, 2)  MAC(w3, 3)
        MAC(w4, 4)  MAC(w5, 5)  MAC(w6, 6)  MAC(w7, 7)
        MAC(w8, 8)  MAC(w9, 9)  MAC(wA, 10) MAC(wB, 11)
        MAC(wC, 12) MAC(wD, 13) MAC(wE, 14) MAC(wF, 15)
#undef MAC
        const float g = (a0 + a1) + (a2 + a3);

        // activation (sigmoid for i,f,o; tanh = 2*sig(2x)-1 for g)
        const float s = __builtin_amdgcn_rcpf(1.0f + __expf(-(g * asc)));
        const float a = fmaf(s, osc, ooff);

        // ---- quad DPP exchange: lane gets gates {gt, gt^1, gt^2, gt^3} ----
        const float s1 = qperm<0xB1>(a);    // quad_perm [1,0,3,2] -> gt^1
        const float s2 = qperm<0x4E>(a);    // quad_perm [2,3,0,1] -> gt^2
        const float s3 = qperm<0x1B>(a);    // quad_perm [3,2,1,0] -> gt^3
        // i*g: even gt -> a*s2, odd gt -> s1*s3
        const float ig = m1 ? (s1 * s3) : (a * s2);
        // f (gate 1): gt=0->s1 1->a 2->s3 3->s2
        const float f  = m1 ? (m2 ? s2 : a) : (m2 ? s3 : s1);
        // o (gate 3): gt=0->s3 1->s2 2->s1 3->a
        const float o  = m1 ? (m2 ? a : s2) : (m2 ? s1 : s3);

        // ---- cell + hidden update (replicated across the quad) ----
        c = fmaf(f, c, ig);
        const float tc = 1.0f - 2.0f * __builtin_amdgcn_rcpf(1.0f + __expf(2.0f * c));
        const float hu = o * tc;
        if (wr_h) h_buf[(t + 1) & 1][u] = hu;
        __syncthreads();
    }

    // head: out = dot(W_lin, h_last) + b_lin
    if (tid < 64) {
        float v = h_buf[T & 1][tid] * W_lin[tid];
#pragma unroll
        for (int m = 32; m >= 1; m >>= 1) v += __shfl_xor(v, m, 64);
        if (tid == 0) out[0] = v + b_lin[0];
    }
}

extern "C" void kernel_launch(void* const* d_in, const int* in_sizes, int n_in,
                              void* d_out, int out_size, void* d_ws, size_t ws_size,
                              hipStream_t stream) {
    const float* seq   = (const float*)d_in[0];
    const float* W_ih  = (const float*)d_in[1];
    const float* W_hh  = (const float*)d_in[2];
    const float* b_ih  = (const float*)d_in[3];
    const float* b_hh  = (const float*)d_in[4];
    const float* W_lin = (const float*)d_in[5];
    const float* b_lin = (const float*)d_in[6];
    float* out = (float*)d_out;
    const int T = in_sizes[0];

    hipLaunchKernelGGL(lstm_seq_kernel, dim3(1), dim3(256), 0, stream,
                       seq, W_ih, W_hh, b_ih, b_hh, W_lin, b_lin, out, T);
}